// Round 6
// baseline (255.796 us; speedup 1.0000x reference)
//
#include <hip/hip_runtime.h>

// MetaPolicyTransformer: B=65536,T=20,M=4,D=4,L=3,H=2,FF=16,S=5. N=B*T seqs.
// R12 = rate-model diagnostic. R6-R11 invariant: issued VALU cycles/wave
// (13,050) = 2.3x the static intent (~5,600 cyc) — unexplained by movs/trans.
// Hypothesis: VOP3P dot2/packed-f16 class issues at 1/2 or 1/4 rate on
// gfx950 while v_fma_f32 is full-rate (HW-verified m07). Experiment: qkv,
// attention (scores/softmax/PV), and out-proj rewritten in scalar f32 fma
// (f32 weight tables in d_ws; zero pk/dot2 in those phases — also deletes
// ~200 pack instrs/seq, a win under every model). FFN kept packed-fp16 as
// control. Precision improves (more f32).
// Pre-committed read: 105-118us => packed-slow (convert FFN next);
// 130-138us => full-rate (revert, attack idle).
// Kept from R10/R11: 1 thread = 1 seq, FULL layer unroll (s_load prefetch),
// bo folded into b1'/b2', layer-0 cls-row qkv precomputed by prep,
// exp2-domain attention (log2e/sqrt2 folded into Wk/bqkv_k), no softmax
// max-subtract (scores bounded; validated R4).

typedef _Float16 h2 __attribute__((ext_vector_type(2)));

// d_ws word layout (4-byte words; fp32 or half2 per word)
enum {
  WF_CLS  = 0,    // 4    fp32: cls + PE row 0 prefolded
  WF_BQKV = 4,    // 36   fp32 biases, k-part pre-scaled by log2e/sqrt2
  WF_B2   = 40,   // 12   b2' = b2 + bo (folded)
  WF_QKV0 = 52,   // 12   fp32: layer-0 cls-row q[4] | k[4] (FS-scaled) | v[4]
  WF_FLAG = 64,   // int: 1 if regional_states fp32
  WF_WQKV = 68,   // 144  fp32 Wqkv (l,j,d) = l*48+j*4+d; k rows FS-scaled
  WF_WO   = 212,  // 48   fp32 Wo (l,i,d) = l*16+i*4+d
  H_B1    = 260,  // 24   half2: (l,p) = b1'[2p],b1'[2p+1], b1' = b1 + W1@bo
  H_W1    = 284,  // 96   half2 PAIR-MAJOR: (l,p,d) = (W1[2p][d], W1[2p+1][d])
  H_W2    = 380,  // 96   half2: (l,i,fpair p) W2[i][2p],[2p+1]
  WF_TOTAL = 476
};

__device__ __forceinline__ float bf2f(unsigned short u) {
  unsigned int x = ((unsigned int)u) << 16;
  float f;
  __builtin_memcpy(&f, &x, 4);
  return f;
}

__device__ __forceinline__ bool is_bf16_packed(const unsigned int* w) {
  int pass = 0;
#pragma unroll
  for (int i = 0; i < 16; ++i) {
    unsigned int lo = w[i] & 0xFFFFu;
    unsigned int e = (lo >> 7) & 0xFFu;
    if (lo == 0u || (e >= 90u && e <= 140u)) ++pass;
  }
  return pass >= 15;
}

__device__ __forceinline__ float dot2(h2 a, h2 b, float c) {
#if __has_builtin(__builtin_amdgcn_fdot2)
  return __builtin_amdgcn_fdot2(a, b, c, false);
#else
  return fmaf((float)a.x, (float)b.x, fmaf((float)a.y, (float)b.y, c));
#endif
}

__device__ __forceinline__ h2 pk(float a, float b) {
  // v_cvt_pkrtz_f16_f32; builtin returns __fp16v2 — bitcast to _Float16v2
  auto t = __builtin_amdgcn_cvt_pkrtz(a, b);
  h2 r;
  __builtin_memcpy(&r, &t, sizeof(r));
  return r;
}

__device__ __forceinline__ h2 relu2(h2 a) {
  h2 z = {(_Float16)0.0f, (_Float16)0.0f};
#if __has_builtin(__builtin_elementwise_max)
  return __builtin_elementwise_max(a, z);  // v_pk_max_f16
#else
  h2 r;
  r.x = a.x > z.x ? a.x : z.x;
  r.y = a.y > z.y ? a.y : z.y;
  return r;
#endif
}

__device__ __forceinline__ float fexp2(float x) {
#if __has_builtin(__builtin_amdgcn_exp2f)
  return __builtin_amdgcn_exp2f(x);
#else
  return __builtin_exp2f(x);
#endif
}

// ---- prep: sniff dtypes, build f32 weight/bias + half2 FFN tables in d_ws.
// Runs every call (d_ws re-poisoned before each timed launch). ----
__global__ void mpt_prep(const void* __restrict__ cls,
                         const void* __restrict__ Wqkv,
                         const void* __restrict__ bqkv,
                         const void* __restrict__ Wo,
                         const void* __restrict__ bo,
                         const void* __restrict__ W1,
                         const void* __restrict__ b1,
                         const void* __restrict__ W2,
                         const void* __restrict__ b2,
                         const void* __restrict__ xin,
                         float* __restrict__ wf) {
  const bool wbf = is_bf16_packed((const unsigned int*)Wqkv);
  const bool xbf = is_bf16_packed((const unsigned int*)xin);
  // log2(e)/sqrt(2): folds the 1/sqrt(hd) score scale and exp->exp2.
  const float FS = 1.44269504088896341f * 0.70710678118654752f;

  for (int w = threadIdx.x; w < WF_TOTAL; w += 256) {
    if (w == WF_FLAG) { ((int*)wf)[w] = xbf ? 0 : 1; continue; }

    auto g = [&](const void* src, int idx) -> float {
      return wbf ? bf2f(((const unsigned short*)src)[idx])
                 : ((const float*)src)[idx];
    };

    if (w < WF_BQKV) {                 // cls + PE row0 {0,1,0,1}
      wf[w] = g(cls, w) + ((w & 1) ? 1.0f : 0.0f);
    } else if (w < WF_B2) {            // bqkv, scale k rows
      int t = w - WF_BQKV;
      float val = g(bqkv, t);
      int j = t % 12;
      if (j >= 4 && j < 8) val *= FS;
      wf[w] = val;
    } else if (w < WF_QKV0) {          // b2' = b2 + bo (bo fold)
      int t = w - WF_B2;
      wf[w] = g(b2, t) + g(bo, t);
    } else if (w < WF_FLAG) {          // layer-0 cls-row qkv constants
      int j = w - WF_QKV0;
      float acc = g(bqkv, j);
#pragma unroll
      for (int d = 0; d < 4; ++d) {
        float xc = g(cls, d) + ((d & 1) ? 1.0f : 0.0f);  // cls + PE row0
        acc = fmaf(g(Wqkv, j * 4 + d), xc, acc);
      }
      if (j >= 4 && j < 8) acc *= FS;  // k rows in log2/sqrt2 domain
      wf[w] = acc;
    } else if (w < WF_WQKV) {          // padding gap
      wf[w] = 0.0f;
    } else if (w < WF_WO) {            // Wqkv f32 (k rows FS-scaled)
      int t = w - WF_WQKV;
      float val = g(Wqkv, t);
      int j = (t % 48) / 4;
      if (j >= 4 && j < 8) val *= FS;
      wf[w] = val;
    } else if (w < H_B1) {             // Wo f32 (torch (L,D,D) row-major)
      wf[w] = g(Wo, w - WF_WO);
    } else if (w < H_W1) {             // b1' pairs: l*8+p -> b1+W1@bo
      int t = w - H_B1, l = t / 8, p = t % 8;
      int f0 = 2 * p, f1 = 2 * p + 1;
      float v0 = g(b1, l * 16 + f0), v1 = g(b1, l * 16 + f1);
#pragma unroll
      for (int d = 0; d < 4; ++d) {
        float bod = g(bo, l * 4 + d);
        v0 = fmaf(g(W1, l * 64 + f0 * 4 + d), bod, v0);
        v1 = fmaf(g(W1, l * 64 + f1 * 4 + d), bod, v1);
      }
      ((h2*)wf)[w] = pk(v0, v1);
    } else if (w < H_W2) {             // W1 pair-major: (l,p,d)
      int t = w - H_W1, l = t / 32, p = (t % 32) / 4, d = t % 4;
      int base = l * 64 + 8 * p + d;
      ((h2*)wf)[w] = pk(g(W1, base), g(W1, base + 4));
    } else {                           // W2: l*64 + i*16 + p*2 (pairs along FF)
      int t = w - H_W2, l = t / 32, i = (t % 32) / 8, p = t % 8;
      int base = l * 64 + i * 16 + p * 2;
      ((h2*)wf)[w] = pk(g(W2, base), g(W2, base + 1));
    }
  }
}

// ---- main: one thread per sequence; qkv/attention/out-proj in scalar f32
// fma (full-rate VALU); FFN hidden kept packed-fp16 (control group). Layer
// loop FULLY UNROLLED. ----
__global__ __launch_bounds__(256) void mpt_main(
    const void* __restrict__ xin,   // (N,16) fp32 (or bf16; flag decides)
    const float* __restrict__ wf,   // prepped tables in d_ws
    float* __restrict__ out,        // [N*4 F_g | N*16 subregion] fp32
    int N) {
  const int n = blockIdx.x * 256 + threadIdx.x;
  if (n >= N) return;

  const int xf32 = ((const int*)wf)[WF_FLAG];  // wave-uniform
  const h2* hw = (const h2*)wf;                // word-indexed half2 view

  // PE rows 1..4 (row 0 prefolded into cls by prep)
  const float pe[4][4] = {
    { 0.8414709848078965f, 0.5403023058681398f, 0.0099998333341667f, 0.9999500004166653f },
    { 0.9092974268256817f,-0.4161468365471424f, 0.0199986666933331f, 0.9998000066665778f },
    { 0.1411200080598672f,-0.9899924966004454f, 0.0299955002024957f, 0.9995500337489875f },
    {-0.7568024953079283f,-0.6536436208636119f, 0.0399893341866342f, 0.9992001066609779f }
  };

  float raw[16];
  if (xf32) {
    const float4* pf = reinterpret_cast<const float4*>((const float*)xin + (size_t)n * 16);
#pragma unroll
    for (int r = 0; r < 4; ++r) {
      float4 t = pf[r];
      raw[r * 4 + 0] = t.x; raw[r * 4 + 1] = t.y;
      raw[r * 4 + 2] = t.z; raw[r * 4 + 3] = t.w;
    }
  } else {
    struct alignas(16) U8 { unsigned short v[8]; };
    const U8* p = reinterpret_cast<const U8*>((const unsigned short*)xin + (size_t)n * 16);
    U8 a0 = p[0], a1 = p[1];
#pragma unroll
    for (int j = 0; j < 8; ++j) {
      raw[j]     = bf2f(a0.v[j]);
      raw[8 + j] = bf2f(a1.v[j]);
    }
  }

  float x[5][4];
#pragma unroll
  for (int d = 0; d < 4; ++d) x[0][d] = wf[WF_CLS + d];  // cls+PE0 prefolded
#pragma unroll
  for (int r = 0; r < 4; ++r)
#pragma unroll
    for (int d = 0; d < 4; ++d) x[1 + r][d] = raw[r * 4 + d] + pe[r][d];

#pragma unroll  // FULL unroll: lets the scheduler prefetch next layer's s_loads
  for (int l = 0; l < 3; ++l) {
    const float* bq  = wf + WF_BQKV + l * 12;
    const float* b2  = wf + WF_B2   + l * 4;   // b2' = b2 + bo
    const float* Wq  = wf + WF_WQKV + l * 48;  // [j*4 + d], k rows FS-scaled
    const float* Wop = wf + WF_WO   + l * 16;  // [i*4 + d]
    const h2* hb1  = hw + H_B1  + l * 8;   // b1' pairs
    const h2* hw1p = hw + H_W1  + l * 32;  // [p*4 + d]
    const h2* hw2  = hw + H_W2  + l * 32;  // [i*8 + p]

    // qkv projection: 4 chained f32 fma per output (k rows pre-scaled)
    float q[5][4], k[5][4], v[5][4];
#pragma unroll
    for (int s = 0; s < 5; ++s) {
      if (l == 0 && s == 0) {  // constant cls row: precomputed by prep
#pragma unroll
        for (int j = 0; j < 4; ++j) {
          q[0][j] = wf[WF_QKV0 + j];
          k[0][j] = wf[WF_QKV0 + 4 + j];
          v[0][j] = wf[WF_QKV0 + 8 + j];
        }
        continue;
      }
#pragma unroll
      for (int j = 0; j < 12; ++j) {
        float a = fmaf(x[s][0], Wq[j * 4 + 0], bq[j]);
        a = fmaf(x[s][1], Wq[j * 4 + 1], a);
        a = fmaf(x[s][2], Wq[j * 4 + 2], a);
        a = fmaf(x[s][3], Wq[j * 4 + 3], a);
        if (j < 4)      q[s][j] = a;
        else if (j < 8) k[s][j - 4] = a;
        else            v[s][j - 8] = a;
      }
    }

    // attention, all f32: head h uses dims {2h,2h+1}; score in exp2 domain
    float o[5][4];
#pragma unroll
    for (int h = 0; h < 2; ++h) {
      const int d0 = 2 * h, d1 = 2 * h + 1;
#pragma unroll
      for (int si = 0; si < 5; ++si) {
        float e[5];
#pragma unroll
        for (int sj = 0; sj < 5; ++sj) {
          float sc = fmaf(q[si][d0], k[sj][d0], q[si][d1] * k[sj][d1]);
          e[sj] = fexp2(sc);
        }
        float den = ((e[0] + e[1]) + (e[2] + e[3])) + e[4];
        float inv = __builtin_amdgcn_rcpf(den);
        float o0 = e[0] * v[0][d0], o1 = e[0] * v[0][d1];
#pragma unroll
        for (int sj = 1; sj < 5; ++sj) {
          o0 = fmaf(e[sj], v[sj][d0], o0);
          o1 = fmaf(e[sj], v[sj][d1], o1);
        }
        o[si][d0] = o0 * inv;
        o[si][d1] = o1 * inv;
      }
    }

    // out-proj + residual in f32 (bo folded into b1'/b2'), then FFN + residual
#pragma unroll
    for (int s = 0; s < 5; ++s) {
      float nx[4];  // nx' = x + o@Wo^T (true nx minus bo)
#pragma unroll
      for (int i = 0; i < 4; ++i) {
        float a = fmaf(o[s][0], Wop[i * 4 + 0], x[s][i]);
        a = fmaf(o[s][1], Wop[i * 4 + 1], a);
        a = fmaf(o[s][2], Wop[i * 4 + 2], a);
        nx[i] = fmaf(o[s][3], Wop[i * 4 + 3], a);
      }

      // FFN (packed-fp16 hidden, unchanged control group)
      h2 xb[4];
      float acc[4];
#pragma unroll
      for (int d = 0; d < 4; ++d) xb[d] = pk(nx[d], nx[d]);
#pragma unroll
      for (int i = 0; i < 4; ++i) acc[i] = b2[i];
#pragma unroll
      for (int p = 0; p < 8; ++p) {
        h2 hc = hb1[p];
#pragma unroll
        for (int d = 0; d < 4; ++d) hc = xb[d] * hw1p[p * 4 + d] + hc;  // v_pk_fma_f16
        h2 hh = relu2(hc);  // v_pk_max_f16
#pragma unroll
        for (int i = 0; i < 4; ++i) acc[i] = dot2(hh, hw2[i * 8 + p], acc[i]);
      }
#pragma unroll
      for (int i = 0; i < 4; ++i) x[s][i] = nx[i] + acc[i];
    }
  }

  // stores (fp32, coalesced dwordx4)
  *reinterpret_cast<float4*>(out + (size_t)n * 4) =
      make_float4(x[0][0], x[0][1], x[0][2], x[0][3]);
  float* sub = out + (size_t)N * 4 + (size_t)n * 16;
#pragma unroll
  for (int r = 0; r < 4; ++r)
    *reinterpret_cast<float4*>(sub + r * 4) =
        make_float4(x[1 + r][0], x[1 + r][1], x[1 + r][2], x[1 + r][3]);
}

extern "C" void kernel_launch(void* const* d_in, const int* in_sizes, int n_in,
                              void* d_out, int out_size, void* d_ws, size_t ws_size,
                              hipStream_t stream) {
  float* wf = (float*)d_ws;

  mpt_prep<<<1, 256, 0, stream>>>(
      d_in[1], d_in[2], d_in[3], d_in[4], d_in[5],
      d_in[6], d_in[7], d_in[8], d_in[9],
      d_in[0],  // regional_states (dtype sniff)
      wf);

  const int N = in_sizes[0] / 16;  // B*T sequences
  mpt_main<<<(N + 255) / 256, 256, 0, stream>>>(
      d_in[0], wf, (float*)d_out, N);
}